// Round 2
// baseline (144.567 us; speedup 1.0000x reference)
//
#include <hip/hip_runtime.h>

// TFAdaptiveAvgPool1D: in [32,1024,4096] f32 -> out [32,1024,512] f32.
// 4096/512 = 8 exactly => out[r,ow] = mean(in[r, 8*ow : 8*ow+8]).
//
// Fully-coalesced variant: every global_load_dwordx4 has lane i at address
// base + i*16B (8 cache lines per wave-instruction instead of 64).
// Window sum = pair of adjacent lanes' float4 sums: shfl_xor(1) + gather shfl.
// Lanes 0..31 store 32 contiguous outputs (128B coalesced store).

__global__ void __launch_bounds__(256)
TFAdaptiveAvgPool1D_40003325395108_kernel(const float4* __restrict__ in4,
                                          float* __restrict__ out,
                                          long long n4 /* input float4 count */) {
    const long long stride = (long long)gridDim.x * blockDim.x;  // float4 units
    const int lane = (int)(threadIdx.x & 63);
    long long i = (long long)blockIdx.x * blockDim.x + threadIdx.x;

    // main sweep: 8 coalesced loads in flight per thread
    for (; i + 7 * stride < n4; i += 8 * stride) {
        float4 a[8];
#pragma unroll
        for (int k = 0; k < 8; ++k) a[k] = in4[i + k * stride];
#pragma unroll
        for (int k = 0; k < 8; ++k) {
            float s = (a[k].x + a[k].y) + (a[k].z + a[k].w);  // half-window sum
            s += __shfl_xor(s, 1);                            // full window sum (both lanes of pair)
            float v = __shfl(s, (lane & 31) * 2) * 0.125f;    // gather to lanes 0..31
            if (lane < 32) {
                long long wb = (i + k * stride) - lane;       // wave's first float4 index
                out[(wb >> 1) + lane] = v;                    // 32 contiguous floats
            }
        }
    }
    // tail (not hit for this shape, kept for generality)
    for (; i < n4; i += stride) {
        float4 a = in4[i];
        float s = (a.x + a.y) + (a.z + a.w);
        s += __shfl_xor(s, 1);
        float v = __shfl(s, (lane & 31) * 2) * 0.125f;
        if (lane < 32) {
            long long wb = i - lane;
            out[(wb >> 1) + lane] = v;
        }
    }
}

extern "C" void kernel_launch(void* const* d_in, const int* in_sizes, int n_in,
                              void* d_out, int out_size, void* d_ws, size_t ws_size,
                              hipStream_t stream) {
    const float4* in4 = (const float4*)d_in[0];  // [32,1024,4096] f32 = 2^25 float4
    float* out = (float*)d_out;                  // [32,1024,512] f32

    const long long n4 = (long long)in_sizes[0] / 4;  // 33,554,432
    const int block = 256;
    const int grid = 2048;  // 2^19 threads; 8*stride = 4,194,304 divides n4 exactly
    TFAdaptiveAvgPool1D_40003325395108_kernel<<<grid, block, 0, stream>>>(in4, out, n4);
}

// Round 3
// 134.217 us; speedup vs baseline: 1.0771x; 1.0771x over previous
//
#include <hip/hip_runtime.h>

// TFAdaptiveAvgPool1D: in [32,1024,4096] f32 -> out [32,1024,512] f32.
// 4096/512 = 8 exactly => out[w] = mean(in[8w : 8w+8]) over the flat array.
//
// One window per thread: two adjacent float4 loads (32B/lane stride -> pairs
// of lanes share a cache line within each instruction: 32 line-req/instr,
// 2x better than the 128B/lane layout, no shuffles). Store is 1 float/lane,
// fully coalesced. 4 windows per thread per iteration for load ILP (8
// outstanding dwordx4).

__global__ void __launch_bounds__(256)
TFAdaptiveAvgPool1D_40003325395108_kernel(const float4* __restrict__ in4,
                                          float* __restrict__ out,
                                          long long nw /* number of windows */) {
    const long long stride = (long long)gridDim.x * blockDim.x;  // in windows
    long long w = (long long)blockIdx.x * blockDim.x + threadIdx.x;

    for (; w + 3 * stride < nw; w += 4 * stride) {
        float4 a[4], b[4];
#pragma unroll
        for (int k = 0; k < 4; ++k) {
            long long wi = w + k * stride;
            a[k] = in4[2 * wi];
            b[k] = in4[2 * wi + 1];
        }
#pragma unroll
        for (int k = 0; k < 4; ++k) {
            long long wi = w + k * stride;
            float s = ((a[k].x + a[k].y) + (a[k].z + a[k].w)) +
                      ((b[k].x + b[k].y) + (b[k].z + b[k].w));
            out[wi] = s * 0.125f;
        }
    }
    for (; w < nw; w += stride) {
        float4 a = in4[2 * w], b = in4[2 * w + 1];
        float s = ((a.x + a.y) + (a.z + a.w)) + ((b.x + b.y) + (b.z + b.w));
        out[w] = s * 0.125f;
    }
}

extern "C" void kernel_launch(void* const* d_in, const int* in_sizes, int n_in,
                              void* d_out, int out_size, void* d_ws, size_t ws_size,
                              hipStream_t stream) {
    const float4* in4 = (const float4*)d_in[0];  // [32,1024,4096] f32
    float* out = (float*)d_out;                  // [32,1024,512] f32

    const long long nw = (long long)out_size;    // 16,777,216 windows
    const int block = 256;
    const int grid = 2048;  // 524288 threads; 4*stride divides nw exactly
    TFAdaptiveAvgPool1D_40003325395108_kernel<<<grid, block, 0, stream>>>(in4, out, nw);
}

// Round 4
// 120.028 us; speedup vs baseline: 1.2045x; 1.1182x over previous
//
#include <hip/hip_runtime.h>

// TFAdaptiveAvgPool1D: in [32,1024,4096] f32 -> out [32,1024,512] f32.
// 4096/512 = 8 => out[w] = mean(in[8w:8w+8]).
//
// R1 structure (best so far: 128B contiguous per lane, one float4-store of 4
// outputs) + 2-deep register pipeline: prefetch next iteration's 8 float4s
// BEFORE computing the current one, so each wave keeps ~16 loads in flight
// instead of stalling a full HBM latency per iteration.
// grid=4096 blocks -> 4 iterations/thread (3 pipelined + epilogue).

__global__ void __launch_bounds__(256)
TFAdaptiveAvgPool1D_40003325395108_kernel(const float4* __restrict__ in4,
                                          float4* __restrict__ out4,
                                          long long n4 /* output float4 count */) {
    const long long stride = (long long)gridDim.x * blockDim.x;
    long long i = (long long)blockIdx.x * blockDim.x + threadIdx.x;
    if (i >= n4) return;

    float4 cur[8];
    {
        const float4* p = in4 + i * 8;
#pragma unroll
        for (int k = 0; k < 8; ++k) cur[k] = p[k];
    }

    for (; i + stride < n4; i += stride) {
        // prefetch next iteration's 128B block (stays in flight during compute)
        float4 nxt[8];
        {
            const float4* p = in4 + (i + stride) * 8;
#pragma unroll
            for (int k = 0; k < 8; ++k) nxt[k] = p[k];
        }
        float4 r;
        r.x = ((cur[0].x + cur[0].y) + (cur[0].z + cur[0].w) +
               (cur[1].x + cur[1].y) + (cur[1].z + cur[1].w)) * 0.125f;
        r.y = ((cur[2].x + cur[2].y) + (cur[2].z + cur[2].w) +
               (cur[3].x + cur[3].y) + (cur[3].z + cur[3].w)) * 0.125f;
        r.z = ((cur[4].x + cur[4].y) + (cur[4].z + cur[4].w) +
               (cur[5].x + cur[5].y) + (cur[5].z + cur[5].w)) * 0.125f;
        r.w = ((cur[6].x + cur[6].y) + (cur[6].z + cur[6].w) +
               (cur[7].x + cur[7].y) + (cur[7].z + cur[7].w)) * 0.125f;
        out4[i] = r;
#pragma unroll
        for (int k = 0; k < 8; ++k) cur[k] = nxt[k];
    }

    // epilogue: last block already in cur
    {
        float4 r;
        r.x = ((cur[0].x + cur[0].y) + (cur[0].z + cur[0].w) +
               (cur[1].x + cur[1].y) + (cur[1].z + cur[1].w)) * 0.125f;
        r.y = ((cur[2].x + cur[2].y) + (cur[2].z + cur[2].w) +
               (cur[3].x + cur[3].y) + (cur[3].z + cur[3].w)) * 0.125f;
        r.z = ((cur[4].x + cur[4].y) + (cur[4].z + cur[4].w) +
               (cur[5].x + cur[5].y) + (cur[5].z + cur[5].w)) * 0.125f;
        r.w = ((cur[6].x + cur[6].y) + (cur[6].z + cur[6].w) +
               (cur[7].x + cur[7].y) + (cur[7].z + cur[7].w)) * 0.125f;
        out4[i] = r;
    }
}

extern "C" void kernel_launch(void* const* d_in, const int* in_sizes, int n_in,
                              void* d_out, int out_size, void* d_ws, size_t ws_size,
                              hipStream_t stream) {
    const float4* in4 = (const float4*)d_in[0];   // [32,1024,4096] f32
    float4* out4 = (float4*)d_out;                // [32,1024,512] f32 as float4

    const long long n4 = (long long)out_size / 4; // 4,194,304
    const int block = 256;
    const int grid = 4096;                        // stride=1,048,576; 4 iters/thread
    TFAdaptiveAvgPool1D_40003325395108_kernel<<<grid, block, 0, stream>>>(in4, out4, n4);
}

// Round 5
// 113.560 us; speedup vs baseline: 1.2731x; 1.0570x over previous
//
#include <hip/hip_runtime.h>

// TFAdaptiveAvgPool1D: in [32,1024,4096] f32 -> out [32,1024,512] f32.
// 4096/512 = 8 => out[w] = mean(in[8w:8w+8]).
//
// Max-TLP, fill-kernel-shaped: one output float4 (4 windows, 128B read) per
// thread, NO loop, NO tail (4,194,304 outputs / 4 = 16384 blocks x 256 exact).
// Keeps VGPR <= 64 so occupancy hits the full 32 waves/CU -- latency hiding
// via TLP instead of per-wave ILP (R4 showed deeper ILP is neutral; R1/R4's
// loop state likely capped occupancy at 16 waves/CU).

__global__ void __launch_bounds__(256)
TFAdaptiveAvgPool1D_40003325395108_kernel(const float4* __restrict__ in4,
                                          float4* __restrict__ out4) {
    const long long i = (long long)blockIdx.x * 256 + threadIdx.x;
    const float4* p = in4 + i * 8;
    float4 a0 = p[0], a1 = p[1], a2 = p[2], a3 = p[3];
    float4 a4 = p[4], a5 = p[5], a6 = p[6], a7 = p[7];
    float4 r;
    r.x = ((a0.x + a0.y) + (a0.z + a0.w) + (a1.x + a1.y) + (a1.z + a1.w)) * 0.125f;
    r.y = ((a2.x + a2.y) + (a2.z + a2.w) + (a3.x + a3.y) + (a3.z + a3.w)) * 0.125f;
    r.z = ((a4.x + a4.y) + (a4.z + a4.w) + (a5.x + a5.y) + (a5.z + a5.w)) * 0.125f;
    r.w = ((a6.x + a6.y) + (a6.z + a6.w) + (a7.x + a7.y) + (a7.z + a7.w)) * 0.125f;
    out4[i] = r;
}

extern "C" void kernel_launch(void* const* d_in, const int* in_sizes, int n_in,
                              void* d_out, int out_size, void* d_ws, size_t ws_size,
                              hipStream_t stream) {
    const float4* in4 = (const float4*)d_in[0];   // [32,1024,4096] f32
    float4* out4 = (float4*)d_out;                // [32,1024,512] f32 as float4

    const int n4 = out_size / 4;                  // 4,194,304
    const int block = 256;
    const int grid = n4 / block;                  // 16384, exact
    TFAdaptiveAvgPool1D_40003325395108_kernel<<<grid, block, 0, stream>>>(in4, out4);
}